// Round 1
// baseline (206.813 us; speedup 1.0000x reference)
//
#include <hip/hip_runtime.h>
#include <math.h>

#define EPSF 1e-6f

constexpr int BSZ = 8, NQ = 900, TT = 256, MT = 2000;
constexpr int NP = BSZ * NQ;  // 7200 predictions

// ---------------- Kernel 1: probs = clip(sigmoid(logits), EPS, 1-EPS) ----------------
__global__ void sigmoid_kernel(const float* __restrict__ in, float* __restrict__ out, int n4) {
    int i = blockIdx.x * blockDim.x + threadIdx.x;
    if (i >= n4) return;
    float4 x = reinterpret_cast<const float4*>(in)[i];
    float4 y;
    y.x = fminf(fmaxf(1.0f / (1.0f + expf(-x.x)), EPSF), 1.0f - EPSF);
    y.y = fminf(fmaxf(1.0f / (1.0f + expf(-x.y)), EPSF), 1.0f - EPSF);
    y.z = fminf(fmaxf(1.0f / (1.0f + expf(-x.z)), EPSF), 1.0f - EPSF);
    y.w = fminf(fmaxf(1.0f / (1.0f + expf(-x.w)), EPSF), 1.0f - EPSF);
    reinterpret_cast<float4*>(out)[i] = y;
}

// ---------------- Kernel 2: norm_labels[m] = labels[m] / (sum_t labels[m,t] + EPS) ----
// one wave (64 lanes) per row; 256 cols = 4 floats/lane (float4)
__global__ void normlab_kernel(const float* __restrict__ lab, float* __restrict__ out) {
    int wave = threadIdx.x >> 6;
    int lane = threadIdx.x & 63;
    int m = blockIdx.x * 4 + wave;  // grid = 500 -> m in [0,2000)
    float4 v = reinterpret_cast<const float4*>(lab)[m * (TT / 4) + lane];
    float s = v.x + v.y + v.z + v.w;
#pragma unroll
    for (int off = 32; off > 0; off >>= 1) s += __shfl_down(s, off);
    float tot = __shfl(s, 0);
    float inv = 1.0f / (tot + EPSF);
    float4 o;
    o.x = v.x * inv; o.y = v.y * inv; o.z = v.z * inv; o.w = v.w * inv;
    reinterpret_cast<float4*>(out)[m * (TT / 4) + lane] = o;
}

// ---------------- Kernel 3: fused cost matrix --------------------------------------
// C[n,m] = 5*L1(cxcywh) - dot(probs[n], nlab[m]) - 2*max(giou, -1)
// 64x64 output tile per block (256 threads, 4x4 register tile), K tiled by 32.
constexpr int BN = 64, BM = 64, BK = 32, PAD = 68;  // PAD=68: +4 floats keeps 16B align, kills k-stride bank conflicts

__global__ __launch_bounds__(256) void cost_kernel(
    const float* __restrict__ probs,  // [NP][TT]
    const float* __restrict__ nlab,   // [MT][TT]
    const float* __restrict__ pbox,   // [NP][4] cxcywh
    const float* __restrict__ tbox,   // [MT][4] cxcywh
    float* __restrict__ out)          // [NP][MT]
{
    __shared__ float As[BK * PAD];
    __shared__ float Bs[BK * PAD];
    const int tid = threadIdx.x;
    const int n0 = blockIdx.x * BN;
    const int m0 = blockIdx.y * BM;
    const int tn = tid & 15;   // 0..15 -> 4 rows each
    const int tm = tid >> 4;   // 0..15 -> 4 cols each
    const int lrow = tid >> 3;       // 0..31 (two passes -> 64 rows)
    const int lk = (tid & 7) * 4;    // float4 offset in k-chunk

    float acc[4][4] = {{0.0f, 0.0f, 0.0f, 0.0f},
                       {0.0f, 0.0f, 0.0f, 0.0f},
                       {0.0f, 0.0f, 0.0f, 0.0f},
                       {0.0f, 0.0f, 0.0f, 0.0f}};

    for (int k0 = 0; k0 < TT; k0 += BK) {
        __syncthreads();
#pragma unroll
        for (int r = 0; r < 2; ++r) {
            int n = lrow + r * 32;
            int gn = n0 + n; if (gn > NP - 1) gn = NP - 1;  // clamp; stores are guarded later
            float4 va = *reinterpret_cast<const float4*>(&probs[gn * TT + k0 + lk]);
            As[(lk + 0) * PAD + n] = va.x;
            As[(lk + 1) * PAD + n] = va.y;
            As[(lk + 2) * PAD + n] = va.z;
            As[(lk + 3) * PAD + n] = va.w;
            int gm = m0 + n; if (gm > MT - 1) gm = MT - 1;
            float4 vb = *reinterpret_cast<const float4*>(&nlab[gm * TT + k0 + lk]);
            Bs[(lk + 0) * PAD + n] = vb.x;
            Bs[(lk + 1) * PAD + n] = vb.y;
            Bs[(lk + 2) * PAD + n] = vb.z;
            Bs[(lk + 3) * PAD + n] = vb.w;
        }
        __syncthreads();
#pragma unroll
        for (int k = 0; k < BK; ++k) {
            float4 a = *reinterpret_cast<const float4*>(&As[k * PAD + tn * 4]);
            float4 b = *reinterpret_cast<const float4*>(&Bs[k * PAD + tm * 4]);
            float av[4] = {a.x, a.y, a.z, a.w};
            float bv[4] = {b.x, b.y, b.z, b.w};
#pragma unroll
            for (int i = 0; i < 4; ++i)
#pragma unroll
                for (int j = 0; j < 4; ++j)
                    acc[i][j] += av[i] * bv[j];
        }
    }

    // -------- epilogue: box costs + write --------
    float acx[4], acy[4], aw[4], ah[4], ax1[4], ay1[4], ax2[4], ay2[4], areaA[4];
#pragma unroll
    for (int i = 0; i < 4; ++i) {
        int gn = n0 + tn * 4 + i; if (gn > NP - 1) gn = NP - 1;
        float4 b = *reinterpret_cast<const float4*>(&pbox[gn * 4]);
        acx[i] = b.x; acy[i] = b.y; aw[i] = b.z; ah[i] = b.w;
        ax1[i] = b.x - 0.5f * b.z; ay1[i] = b.y - 0.5f * b.w;
        ax2[i] = b.x + 0.5f * b.z; ay2[i] = b.y + 0.5f * b.w;
        areaA[i] = (ax2[i] - ax1[i]) * (ay2[i] - ay1[i]);
    }
    float bcx[4], bcy[4], bw[4], bh[4], bx1[4], by1[4], bx2[4], by2[4], areaB[4];
#pragma unroll
    for (int j = 0; j < 4; ++j) {
        int gm = m0 + tm * 4 + j; if (gm > MT - 1) gm = MT - 1;
        float4 b = *reinterpret_cast<const float4*>(&tbox[gm * 4]);
        bcx[j] = b.x; bcy[j] = b.y; bw[j] = b.z; bh[j] = b.w;
        bx1[j] = b.x - 0.5f * b.z; by1[j] = b.y - 0.5f * b.w;
        bx2[j] = b.x + 0.5f * b.z; by2[j] = b.y + 0.5f * b.w;
        areaB[j] = (bx2[j] - bx1[j]) * (by2[j] - by1[j]);
    }

#pragma unroll
    for (int i = 0; i < 4; ++i) {
        int gn = n0 + tn * 4 + i;
        int gm = m0 + tm * 4;
        if (gn < NP && gm < MT) {   // MT%4==0 and gm%4==0 -> full float4 in-bounds
            float res[4];
#pragma unroll
            for (int j = 0; j < 4; ++j) {
                float l1 = fabsf(acx[i] - bcx[j]) + fabsf(acy[i] - bcy[j]) +
                           fabsf(aw[i]  - bw[j])  + fabsf(ah[i]  - bh[j]);
                float ltx = fmaxf(ax1[i], bx1[j]), lty = fmaxf(ay1[i], by1[j]);
                float rbx = fminf(ax2[i], bx2[j]), rby = fminf(ay2[i], by2[j]);
                float iw = fmaxf(rbx - ltx, 0.0f), ih = fmaxf(rby - lty, 0.0f);
                float inter = iw * ih;
                float uni = areaA[i] + areaB[j] - inter;
                float iou = inter / (uni + EPSF);
                float ex1 = fminf(ax1[i], bx1[j]), ey1 = fminf(ay1[i], by1[j]);
                float ex2 = fmaxf(ax2[i], bx2[j]), ey2 = fmaxf(ay2[i], by2[j]);
                float ew = fmaxf(ex2 - ex1, 0.0f), eh = fmaxf(ey2 - ey1, 0.0f);
                float areaE = ew * eh;
                float giou = iou - (areaE - uni) / (areaE + EPSF);
                res[j] = 5.0f * l1 - acc[i][j] - 2.0f * fmaxf(giou, -1.0f);
            }
            float4 o; o.x = res[0]; o.y = res[1]; o.z = res[2]; o.w = res[3];
            *reinterpret_cast<float4*>(&out[gn * MT + gm]) = o;
        }
    }
}

extern "C" void kernel_launch(void* const* d_in, const int* in_sizes, int n_in,
                              void* d_out, int out_size, void* d_ws, size_t ws_size,
                              hipStream_t stream) {
    const float* pred_logits = (const float*)d_in[0];  // [8,900,256]
    const float* pred_boxes  = (const float*)d_in[1];  // [8,900,4]
    const float* tgt_boxes   = (const float*)d_in[2];  // [2000,4]
    const float* tgt_labels  = (const float*)d_in[3];  // [2000,256]
    float* out = (float*)d_out;                        // [7200,2000]

    float* probs   = (float*)d_ws;          // 7200*256 floats
    float* normlab = probs + NP * TT;       // 2000*256 floats  (total ~9.4 MB)

    {
        int n4 = NP * TT / 4;
        sigmoid_kernel<<<(n4 + 255) / 256, 256, 0, stream>>>(pred_logits, probs, n4);
    }
    normlab_kernel<<<MT / 4, 256, 0, stream>>>(tgt_labels, normlab);

    dim3 grid((NP + BN - 1) / BN, (MT + BM - 1) / BM);  // 113 x 32
    cost_kernel<<<grid, 256, 0, stream>>>(probs, normlab, pred_boxes, tgt_boxes, out);
}

// Round 2
// 128.373 us; speedup vs baseline: 1.6110x; 1.6110x over previous
//
#include <hip/hip_runtime.h>
#include <math.h>

#define EPSF 1e-6f

typedef __attribute__((ext_vector_type(8))) short bf16x8;   // 8 bf16 = 4 VGPR (MFMA A/B frag)
typedef __attribute__((ext_vector_type(4))) float f32x4;    // MFMA C/D frag
typedef __attribute__((ext_vector_type(4))) unsigned short u16x4;
typedef __attribute__((ext_vector_type(8))) unsigned short u16x8;

constexpr int TT = 256, MT = 2000, NP = 7200;

static __device__ __forceinline__ unsigned short f2bf(float f) {
    // round-to-nearest-even bf16 (inputs are finite, positive here)
    unsigned int u = __float_as_uint(f);
    u += 0x7FFFu + ((u >> 16) & 1u);
    return (unsigned short)(u >> 16);
}
static __device__ __forceinline__ float frcp(float x) { return __builtin_amdgcn_rcpf(x); }

// ---------------- Kernel 1: probs = clip(sigmoid(logits)) -> bf16 ----------------
__global__ __launch_bounds__(256) void sigmoid_bf16_kernel(const float* __restrict__ in,
                                                           unsigned short* __restrict__ out) {
    int i = (blockIdx.x * 256 + threadIdx.x) * 8;   // grid sized exactly: no guard needed
    float4 x0 = *reinterpret_cast<const float4*>(in + i);
    float4 x1 = *reinterpret_cast<const float4*>(in + i + 4);
    float v[8] = {x0.x, x0.y, x0.z, x0.w, x1.x, x1.y, x1.z, x1.w};
    u16x8 o;
#pragma unroll
    for (int j = 0; j < 8; ++j) {
        float s = frcp(1.0f + __expf(-v[j]));
        s = fminf(fmaxf(s, EPSF), 1.0f - EPSF);
        o[j] = f2bf(s);
    }
    *reinterpret_cast<u16x8*>(out + i) = o;
}

// ---------------- Kernel 2: norm_labels -> bf16 (one wave per row) ----------------
__global__ __launch_bounds__(256) void normlab_bf16_kernel(const float* __restrict__ lab,
                                                           unsigned short* __restrict__ out) {
    int wave = threadIdx.x >> 6;
    int lane = threadIdx.x & 63;
    int m = blockIdx.x * 4 + wave;              // grid = 500 -> m in [0,2000)
    float4 v = reinterpret_cast<const float4*>(lab)[m * (TT / 4) + lane];
    float s = v.x + v.y + v.z + v.w;
#pragma unroll
    for (int off = 32; off > 0; off >>= 1) s += __shfl_down(s, off);
    float inv = frcp(__shfl(s, 0) + EPSF);
    u16x4 o;
    o[0] = f2bf(v.x * inv); o[1] = f2bf(v.y * inv);
    o[2] = f2bf(v.z * inv); o[3] = f2bf(v.w * inv);
    *reinterpret_cast<u16x4*>(out + m * TT + lane * 4) = o;
}

// ---------------- Kernel 3: MFMA cost matrix ----------------
// C[n,m] = 5*L1 - dot(probs[n], nlab[m]) - 2*max(giou, -1)
// 128x128 tile / block, 4 waves in 2x2, each wave 64x64 via 4x4 mfma_16x16x32 tiles.
constexpr int BN = 128, BM = 128, BK = 64;
constexpr int LDT = BK + 8;   // +8 bf16 (16B) pad: balanced 8-access/bank for b128 r/w

__global__ __launch_bounds__(256) void cost_mfma_kernel(
    const unsigned short* __restrict__ A,   // probs bf16 [NP][TT]
    const unsigned short* __restrict__ B,   // nlab  bf16 [MT][TT]
    const float* __restrict__ pbox,         // [NP][4] cxcywh
    const float* __restrict__ tbox,         // [MT][4] cxcywh
    float* __restrict__ out)                // [NP][MT] fp32
{
    __shared__ __align__(16) unsigned short As[BN * LDT];
    __shared__ __align__(16) unsigned short Bs[BM * LDT];
    const int tid = threadIdx.x;
    const int n0 = blockIdx.x * BN;
    const int m0 = blockIdx.y * BM;
    const int lane = tid & 63, wave = tid >> 6;
    const int wr = wave & 1, wc = wave >> 1;        // wave's 64x64 quadrant
    const int fr = lane & 15, quad = lane >> 4;     // fragment row / quad
    const int sc = tid & 7;                         // staging chunk (8 bf16)
    const int sr = tid >> 3;                        // staging row base 0..31

    f32x4 acc[4][4] = {};

    for (int k0 = 0; k0 < TT; k0 += BK) {
        __syncthreads();
#pragma unroll
        for (int p = 0; p < 4; ++p) {
            int row = sr + p * 32;
            int gn = n0 + row; if (gn > NP - 1) gn = NP - 1;   // clamp; stores guarded later
            bf16x8 va = *reinterpret_cast<const bf16x8*>(&A[gn * TT + k0 + sc * 8]);
            *reinterpret_cast<bf16x8*>(&As[row * LDT + sc * 8]) = va;
            int gm = m0 + row; if (gm > MT - 1) gm = MT - 1;
            bf16x8 vb = *reinterpret_cast<const bf16x8*>(&B[gm * TT + k0 + sc * 8]);
            *reinterpret_cast<bf16x8*>(&Bs[row * LDT + sc * 8]) = vb;
        }
        __syncthreads();
#pragma unroll
        for (int ks = 0; ks < 2; ++ks) {
            bf16x8 af[4], bf[4];
#pragma unroll
            for (int t = 0; t < 4; ++t) {
                af[t] = *reinterpret_cast<const bf16x8*>(
                    &As[(wr * 64 + t * 16 + fr) * LDT + ks * 32 + quad * 8]);
                bf[t] = *reinterpret_cast<const bf16x8*>(
                    &Bs[(wc * 64 + t * 16 + fr) * LDT + ks * 32 + quad * 8]);
            }
#pragma unroll
            for (int ti = 0; ti < 4; ++ti)
#pragma unroll
                for (int tj = 0; tj < 4; ++tj)
                    acc[ti][tj] = __builtin_amdgcn_mfma_f32_16x16x32_bf16(
                        af[ti], bf[tj], acc[ti][tj], 0, 0, 0);
        }
    }

    // -------- epilogue: per-lane column boxes (4), loop over 16 rows --------
    float bcx[4], bcy[4], bww[4], bhh[4], bx1[4], by1[4], bx2[4], by2[4], areaB[4];
    int mj[4]; bool mv[4];
#pragma unroll
    for (int tj = 0; tj < 4; ++tj) {
        int gm = m0 + wc * 64 + tj * 16 + fr;
        mv[tj] = gm < MT;
        int g = mv[tj] ? gm : MT - 1;
        float4 b = *reinterpret_cast<const float4*>(&tbox[g * 4]);
        bcx[tj] = b.x; bcy[tj] = b.y; bww[tj] = b.z; bhh[tj] = b.w;
        bx1[tj] = b.x - 0.5f * b.z; by1[tj] = b.y - 0.5f * b.w;
        bx2[tj] = b.x + 0.5f * b.z; by2[tj] = b.y + 0.5f * b.w;
        areaB[tj] = (bx2[tj] - bx1[tj]) * (by2[tj] - by1[tj]);
        mj[tj] = gm;
    }

#pragma unroll
    for (int ti = 0; ti < 4; ++ti) {
#pragma unroll
        for (int r = 0; r < 4; ++r) {
            int p = n0 + wr * 64 + ti * 16 + quad * 4 + r;   // C/D layout: row = quad*4 + reg
            if (p >= NP) continue;
            float4 pb = *reinterpret_cast<const float4*>(&pbox[p * 4]);
            float ax1 = pb.x - 0.5f * pb.z, ay1 = pb.y - 0.5f * pb.w;
            float ax2 = pb.x + 0.5f * pb.z, ay2 = pb.y + 0.5f * pb.w;
            float areaA = (ax2 - ax1) * (ay2 - ay1);
#pragma unroll
            for (int tj = 0; tj < 4; ++tj) {
                if (!mv[tj]) continue;
                float l1 = fabsf(pb.x - bcx[tj]) + fabsf(pb.y - bcy[tj]) +
                           fabsf(pb.z - bww[tj]) + fabsf(pb.w - bhh[tj]);
                float ltx = fmaxf(ax1, bx1[tj]), lty = fmaxf(ay1, by1[tj]);
                float rbx = fminf(ax2, bx2[tj]), rby = fminf(ay2, by2[tj]);
                float iw = fmaxf(rbx - ltx, 0.0f), ih = fmaxf(rby - lty, 0.0f);
                float inter = iw * ih;
                float uni = areaA + areaB[tj] - inter;
                float iou = inter * frcp(uni + EPSF);
                float ex1 = fminf(ax1, bx1[tj]), ey1 = fminf(ay1, by1[tj]);
                float ex2 = fmaxf(ax2, bx2[tj]), ey2 = fmaxf(ay2, by2[tj]);
                float ew = fmaxf(ex2 - ex1, 0.0f), eh = fmaxf(ey2 - ey1, 0.0f);
                float areaE = ew * eh;
                float giou = iou - (areaE - uni) * frcp(areaE + EPSF);
                float res = 5.0f * l1 - acc[ti][tj][r] - 2.0f * fmaxf(giou, -1.0f);
                out[p * MT + mj[tj]] = res;   // col = lane&15: 16 lanes contiguous
            }
        }
    }
}

extern "C" void kernel_launch(void* const* d_in, const int* in_sizes, int n_in,
                              void* d_out, int out_size, void* d_ws, size_t ws_size,
                              hipStream_t stream) {
    const float* pred_logits = (const float*)d_in[0];  // [8,900,256]
    const float* pred_boxes  = (const float*)d_in[1];  // [8,900,4]
    const float* tgt_boxes   = (const float*)d_in[2];  // [2000,4]
    const float* tgt_labels  = (const float*)d_in[3];  // [2000,256]
    float* out = (float*)d_out;                        // [7200,2000]

    unsigned short* probs = (unsigned short*)d_ws;     // 7200*256 bf16 (3.7 MB)
    unsigned short* nlab  = probs + NP * TT;           // 2000*256 bf16 (1.0 MB)

    sigmoid_bf16_kernel<<<NP * TT / (256 * 8), 256, 0, stream>>>(pred_logits, probs);  // 900 blocks
    normlab_bf16_kernel<<<MT / 4, 256, 0, stream>>>(tgt_labels, nlab);                 // 500 blocks

    dim3 grid((NP + BN - 1) / BN, (MT + BM - 1) / BM);  // 57 x 16 = 912 blocks
    cost_mfma_kernel<<<grid, 256, 0, stream>>>(probs, nlab, pred_boxes, tgt_boxes, out);
}